// Round 7
// baseline (90.357 us; speedup 1.0000x reference)
//
#include <hip/hip_runtime.h>
#include <hip/hip_bf16.h>

#define VOCAB 50000
#define HID   256
#define BATCH 512
#define GH    768   // 3*H

typedef __attribute__((ext_vector_type(8))) __bf16 bf16x8;
typedef __attribute__((ext_vector_type(4))) float f32x4;
typedef __attribute__((ext_vector_type(4))) unsigned int u32x4;

union BFrag {
    bf16x8 v;
    u32x4  q;
    unsigned short u[8];
};

__device__ __forceinline__ unsigned short f2bf(float f) {
    unsigned int x = __builtin_bit_cast(unsigned int, f);
    x += 0x7FFFu + ((x >> 16) & 1u);          // round-to-nearest-even
    return (unsigned short)(x >> 16);
}

__device__ __forceinline__ float fast_sigmoid(float x) {
    return 1.0f / (1.0f + __expf(-x));
}
__device__ __forceinline__ float fast_tanh(float x) {
    return 1.0f - 2.0f / (1.0f + __expf(2.0f * x));
}

__device__ __forceinline__ void cvt8(BFrag& t, f32x4 lo, f32x4 hi) {
    t.u[0] = f2bf(lo.x); t.u[1] = f2bf(lo.y);
    t.u[2] = f2bf(lo.z); t.u[3] = f2bf(lo.w);
    t.u[4] = f2bf(hi.x); t.u[5] = f2bf(hi.y);
    t.u[6] = f2bf(hi.z); t.u[7] = f2bf(hi.w);
}

// One 64x64 output tile per block. No loops over tiles: grid.x = row-chunk
// (fastest-varying -> the 8 blocks sharing a B-tile dispatch adjacently),
// grid.y = col-tile. 4 waves; wave w owns cols [w*16, w*16+16). Per block:
// load 8 B-frags/wave (used once), stage A 64x256 via swizzled LDS (32 KB,
// R1-verified conflict-free), 32 MFMA/wave, 16 stores/thread. Small VGPR
// footprint + 4 blocks/CU -> high TLP for the HBM store stream.
// EPI 0: raw f32 store   1: tanh(acc + bias[col])
// ASRC 0: A f32 row-major  1: A bf16 row-major
template <int EPI, int ASRC>
__global__ __launch_bounds__(256, 4) void gemm_tile(
    const void* __restrict__ Asrc, const float* __restrict__ Bm,
    float* __restrict__ C, const float* __restrict__ bias, int Ncols)
{
    __shared__ char ldsA[64 * 512];           // 64 rows x 256 bf16, swizzled

    const int tid  = threadIdx.x;
    const int wid  = tid >> 6;
    const int lane = tid & 63;
    const int r    = lane & 15;
    const int g    = lane >> 4;
    const int mbase = blockIdx.x * 64;
    const int col   = blockIdx.y * 64 + wid * 16 + r;
    const int bcol  = col < Ncols ? col : (Ncols - 1);

    // ---- B fragments: 8 per wave, load + convert once ----
    BFrag bf[8];
    {
        const f32x4* wrow = reinterpret_cast<const f32x4*>(Bm + (size_t)bcol * 256);
        #pragma unroll
        for (int kk = 0; kk < 8; kk++)
            cvt8(bf[kk], wrow[kk * 8 + g * 2], wrow[kk * 8 + g * 2 + 1]);
    }
    float biasv = 0.0f;
    if (EPI == 1) biasv = bias[bcol];

    // ---- stage A tile (64 x 256) into swizzled LDS ----
    if (ASRC == 1) {
        const u32x4* src = reinterpret_cast<const u32x4*>(
            (const unsigned short*)Asrc + (size_t)mbase * 256);
        #pragma unroll
        for (int i = 0; i < 8; i++) {
            int u = tid + i * 256;            // 0..2047 16B units
            int row = u >> 5, c16 = u & 31;
            u32x4 vv = src[u];
            int byte = (row * 512 + c16 * 16) ^ ((row & 7) << 4);
            *reinterpret_cast<u32x4*>(&ldsA[byte]) = vv;
        }
    } else {
        const f32x4* src = reinterpret_cast<const f32x4*>(
            (const float*)Asrc + (size_t)mbase * 256);
        #pragma unroll
        for (int i = 0; i < 8; i++) {
            int u = tid + i * 256;
            int row = u >> 5, c16 = u & 31;
            BFrag t; cvt8(t, src[2 * u], src[2 * u + 1]);
            int byte = (row * 512 + c16 * 16) ^ ((row & 7) << 4);
            *reinterpret_cast<u32x4*>(&ldsA[byte]) = t.q;
        }
    }
    __syncthreads();

    // ---- 32 MFMA: 4 row-fragments x 8 k-steps ----
    f32x4 acc[4];
    #pragma unroll
    for (int m = 0; m < 4; m++) acc[m] = (f32x4){0.f, 0.f, 0.f, 0.f};

    #pragma unroll
    for (int kk = 0; kk < 8; kk++) {
        #pragma unroll
        for (int m = 0; m < 4; m++) {
            int arow = m * 16 + r;
            int byte = (arow * 512 + kk * 64 + g * 16) ^ ((arow & 7) << 4);
            BFrag a;
            a.q = *reinterpret_cast<const u32x4*>(&ldsA[byte]);
            acc[m] = __builtin_amdgcn_mfma_f32_16x16x32_bf16(a.v, bf[kk].v, acc[m], 0, 0, 0);
        }
    }

    // ---- epilogue: 16 dword stores, full 64B lines per g-group ----
    if (col < Ncols) {
        #pragma unroll
        for (int m = 0; m < 4; m++) {
            #pragma unroll
            for (int j = 0; j < 4; j++) {
                int row = mbase + m * 16 + g * 4 + j;
                float v = acc[m][j];
                if (EPI == 1) v = fast_tanh(v + biasv);
                C[(size_t)row * Ncols + col] = v;
            }
        }
    }
}

// K2: GRU gates. One block per batch row, thread = k. Writes h1 (f32, d_out
// tail) and h1 bf16 row-major (K3's A operand).
__global__ __launch_bounds__(256) void gru_gate(
    const int* __restrict__ inp, const float* __restrict__ hidden,
    const float* __restrict__ w_ih, const float* __restrict__ b_ih,
    const float* __restrict__ b_hh, const float* __restrict__ hproj,
    float* __restrict__ h1out, unsigned short* __restrict__ h1bf)
{
    const int b = blockIdx.x;
    const int k = threadIdx.x;
    const int c = inp[b];

    float xr = w_ih[(size_t)k * VOCAB + c]         + b_ih[k];
    float xz = w_ih[(size_t)(k + 256) * VOCAB + c] + b_ih[k + 256];
    float xn = w_ih[(size_t)(k + 512) * VOCAB + c] + b_ih[k + 512];

    float hr = hproj[b * GH + k]       + b_hh[k];
    float hz = hproj[b * GH + 256 + k] + b_hh[k + 256];
    float hn = hproj[b * GH + 512 + k] + b_hh[k + 512];

    float rg = fast_sigmoid(xr + hr);
    float zg = fast_sigmoid(xz + hz);
    float ng = fast_tanh(xn + rg * hn);
    float h0 = hidden[b * HID + k];
    float h1 = (1.0f - zg) * ng + zg * h0;

    h1out[b * HID + k] = h1;
    h1bf[b * HID + k]  = f2bf(h1);
}

extern "C" void kernel_launch(void* const* d_in, const int* in_sizes, int n_in,
                              void* d_out, int out_size, void* d_ws, size_t ws_size,
                              hipStream_t stream) {
    const int*   input  = (const int*)  d_in[0];
    // d_in[1] = target (unused)
    const float* hidden = (const float*)d_in[2];
    const float* w_ih   = (const float*)d_in[3];
    const float* w_hh   = (const float*)d_in[4];
    const float* b_ih   = (const float*)d_in[5];
    const float* b_hh   = (const float*)d_in[6];
    const float* w_out  = (const float*)d_in[7];
    const float* b_out  = (const float*)d_in[8];

    float* logit = (float*)d_out;                            // [512, 50000]
    float* h1    = (float*)d_out + (size_t)BATCH * VOCAB;    // [512, 256]

    float*          hproj = (float*)d_ws;                                   // 1.5 MB
    unsigned short* h1bf  = (unsigned short*)((char*)d_ws + (size_t)BATCH * GH * 4);

    // K1: hproj = h0 @ w_hh^T   (512 x 768, K=256) — 96 one-tile blocks
    dim3 g1(BATCH / 64, GH / 64);           // (8, 12)
    gemm_tile<0, 0><<<g1, 256, 0, stream>>>(hidden, w_hh, hproj, nullptr, GH);

    // K2: gates -> h1 (f32) + h1bf (row-major bf16)
    gru_gate<<<BATCH, 256, 0, stream>>>(input, hidden, w_ih, b_ih, b_hh, hproj,
                                        h1, h1bf);

    // K3: logit = tanh(h1 @ w_out^T + b_out) — 6256 one-tile blocks
    dim3 g3(BATCH / 64, (VOCAB + 63) / 64); // (8, 782)
    gemm_tile<1, 1><<<g3, 256, 0, stream>>>(h1bf, w_out, logit, b_out, VOCAB);
}

// Round 8
// 61.188 us; speedup vs baseline: 1.4767x; 1.4767x over previous
//
#include <hip/hip_runtime.h>
#include <hip/hip_bf16.h>

#define VOCAB 50000
#define HID   256
#define BATCH 512
#define GH    768   // 3*H

typedef __attribute__((ext_vector_type(8))) __bf16 bf16x8;
typedef __attribute__((ext_vector_type(4))) float f32x4;
typedef __attribute__((ext_vector_type(4))) unsigned int u32x4;

union BFrag {
    bf16x8 v;
    u32x4  q;
    __bf16 b[8];
};

__device__ __forceinline__ float fast_sigmoid(float x) {
    return 1.0f / (1.0f + __expf(-x));
}
__device__ __forceinline__ float fast_tanh(float x) {
    return 1.0f - 2.0f / (1.0f + __expf(2.0f * x));
}

// 8 consecutive f32 -> one bf16x8 fragment via native casts (v_cvt_pk_bf16_f32).
__device__ __forceinline__ void cvt8(BFrag& t, f32x4 lo, f32x4 hi) {
    t.b[0] = (__bf16)lo.x; t.b[1] = (__bf16)lo.y;
    t.b[2] = (__bf16)lo.z; t.b[3] = (__bf16)lo.w;
    t.b[4] = (__bf16)hi.x; t.b[5] = (__bf16)hi.y;
    t.b[6] = (__bf16)hi.z; t.b[7] = (__bf16)hi.w;
}

// C[M x Ncols] = A[M x 256] @ Bm[Ncols x 256]^T   (K=256 whole, no K-loop)
// One block per 64-col tile (B fetched from HBM exactly once, XCD-proof);
// loop over mChunks 64-row chunks of A staged via swizzled 32KB LDS.
// Raw s_barrier (no vmcnt drain!): stores stream freely across chunks; next
// chunk's A-loads issue after barrier #2 and hide under 32 MFMAs; compiler's
// counted vmcnt guards the ds_write of the loaded regs.
// EPI 0: raw f32 store   1: tanh(acc + bias[col])
// ASRC 0: A f32 row-major  1: A bf16 row-major
template <int EPI, int ASRC>
__global__ __launch_bounds__(256, 4) void gemm_col(
    const void* __restrict__ Asrc, const float* __restrict__ Bm,
    float* __restrict__ C, const float* __restrict__ bias,
    int Ncols, int mChunks)
{
    __shared__ char ldsA[64 * 512];           // 64 rows x 256 bf16, swizzled

    const int tid  = threadIdx.x;
    const int wid  = tid >> 6;
    const int lane = tid & 63;
    const int r    = lane & 15;
    const int g    = lane >> 4;
    const int col  = blockIdx.x * 64 + wid * 16 + r;
    const int bcol = col < Ncols ? col : (Ncols - 1);

    // ---- B fragments: 8 per wave, load + convert once, stay in regs ----
    BFrag bf[8];
    {
        const f32x4* wrow = reinterpret_cast<const f32x4*>(Bm + (size_t)bcol * 256);
        #pragma unroll
        for (int kk = 0; kk < 8; kk++)
            cvt8(bf[kk], wrow[kk * 8 + g * 2], wrow[kk * 8 + g * 2 + 1]);
    }
    float biasv = 0.0f;
    if (EPI == 1) biasv = bias[bcol];

    // ---- staging regs (single set; load(c+1) overlaps compute(c)) ----
    u32x4 areg[8];
    auto load_chunk = [&](int c) {
        const int mbase = (blockIdx.y * mChunks + c) * 64;
        if (ASRC == 1) {
            const u32x4* src = reinterpret_cast<const u32x4*>(
                (const unsigned short*)Asrc + (size_t)mbase * 256);
            #pragma unroll
            for (int i = 0; i < 8; i++) areg[i] = src[tid + i * 256];
        } else {
            const f32x4* src = reinterpret_cast<const f32x4*>(
                (const float*)Asrc + (size_t)mbase * 256);
            #pragma unroll
            for (int i = 0; i < 8; i++) {
                int u = tid + i * 256;
                BFrag t; cvt8(t, src[2 * u], src[2 * u + 1]);
                areg[i] = t.q;
            }
        }
    };
    auto write_lds = [&]() {
        #pragma unroll
        for (int i = 0; i < 8; i++) {
            int u = tid + i * 256;            // 0..2047 16B units
            int row = u >> 5, j = u & 31;
            int byte = row * 512 + ((j ^ (row & 7)) << 4);
            *reinterpret_cast<u32x4*>(&ldsA[byte]) = areg[i];
        }
    };

    load_chunk(0);

    for (int c = 0; c < mChunks; c++) {
        if (c > 0)                             // buf free: all reads of c-1 done
            asm volatile("s_barrier" ::: "memory");

        write_lds();                           // compiler waits vmcnt for areg
        asm volatile("s_waitcnt lgkmcnt(0)\n\ts_barrier" ::: "memory");

        if (c + 1 < mChunks) load_chunk(c + 1);   // hide load under MFMAs

        f32x4 acc[4];
        #pragma unroll
        for (int m = 0; m < 4; m++) acc[m] = (f32x4){0.f, 0.f, 0.f, 0.f};

        #pragma unroll
        for (int kk = 0; kk < 8; kk++) {
            #pragma unroll
            for (int m = 0; m < 4; m++) {
                int arow = m * 16 + r;
                int byte = arow * 512 + (((kk * 4 + g) ^ (arow & 7)) << 4);
                BFrag a;
                a.q = *reinterpret_cast<const u32x4*>(&ldsA[byte]);
                acc[m] = __builtin_amdgcn_mfma_f32_16x16x32_bf16(a.v, bf[kk].v, acc[m], 0, 0, 0);
            }
        }

        // epilogue: stores stream out, never drained inside the loop
        if (col < Ncols) {
            const int rowbase = (blockIdx.y * mChunks + c) * 64;
            #pragma unroll
            for (int m = 0; m < 4; m++) {
                #pragma unroll
                for (int j = 0; j < 4; j++) {
                    float v = acc[m][j];
                    if (EPI == 1) v = fast_tanh(v + biasv);
                    C[(size_t)(rowbase + m * 16 + g * 4 + j) * Ncols + col] = v;
                }
            }
        }
    }
}

// K2: GRU gates. One block per batch row, thread = k. Writes h1 (f32, d_out
// tail) and h1 bf16 row-major (K3's A operand).
__global__ __launch_bounds__(256) void gru_gate(
    const int* __restrict__ inp, const float* __restrict__ hidden,
    const float* __restrict__ w_ih, const float* __restrict__ b_ih,
    const float* __restrict__ b_hh, const float* __restrict__ hproj,
    float* __restrict__ h1out, unsigned short* __restrict__ h1bf)
{
    const int b = blockIdx.x;
    const int k = threadIdx.x;
    const int c = inp[b];

    float xr = w_ih[(size_t)k * VOCAB + c]         + b_ih[k];
    float xz = w_ih[(size_t)(k + 256) * VOCAB + c] + b_ih[k + 256];
    float xn = w_ih[(size_t)(k + 512) * VOCAB + c] + b_ih[k + 512];

    float hr = hproj[b * GH + k]       + b_hh[k];
    float hz = hproj[b * GH + 256 + k] + b_hh[k + 256];
    float hn = hproj[b * GH + 512 + k] + b_hh[k + 512];

    float rg = fast_sigmoid(xr + hr);
    float zg = fast_sigmoid(xz + hz);
    float ng = fast_tanh(xn + rg * hn);
    float h0 = hidden[b * HID + k];
    float h1 = (1.0f - zg) * ng + zg * h0;

    h1out[b * HID + k] = h1;
    __bf16 hb = (__bf16)h1;
    h1bf[b * HID + k] = __builtin_bit_cast(unsigned short, hb);
}

extern "C" void kernel_launch(void* const* d_in, const int* in_sizes, int n_in,
                              void* d_out, int out_size, void* d_ws, size_t ws_size,
                              hipStream_t stream) {
    const int*   input  = (const int*)  d_in[0];
    // d_in[1] = target (unused)
    const float* hidden = (const float*)d_in[2];
    const float* w_ih   = (const float*)d_in[3];
    const float* w_hh   = (const float*)d_in[4];
    const float* b_ih   = (const float*)d_in[5];
    const float* b_hh   = (const float*)d_in[6];
    const float* w_out  = (const float*)d_in[7];
    const float* b_out  = (const float*)d_in[8];

    float* logit = (float*)d_out;                            // [512, 50000]
    float* h1    = (float*)d_out + (size_t)BATCH * VOCAB;    // [512, 256]

    float*          hproj = (float*)d_ws;                                   // 1.5 MB
    unsigned short* h1bf  = (unsigned short*)((char*)d_ws + (size_t)BATCH * GH * 4);

    // K1: hproj = h0 @ w_hh^T   (512 x 768, K=256) — 96 blocks, mChunks = 1
    dim3 g1(GH / 64, BATCH / 64);           // (12, 8)
    gemm_col<0, 0><<<g1, 256, 0, stream>>>(hidden, w_hh, hproj, nullptr, GH, 1);

    // K2: gates -> h1 (f32) + h1bf (row-major bf16)
    gru_gate<<<BATCH, 256, 0, stream>>>(input, hidden, w_ih, b_ih, b_hh, hproj,
                                        h1, h1bf);

    // K3: logit = tanh(h1 @ w_out^T + b_out) — 782 col-tile blocks, 8 chunks
    dim3 g3((VOCAB + 63) / 64, 1);
    gemm_col<1, 1><<<g3, 256, 0, stream>>>(h1bf, w_out, logit, b_out, VOCAB, 8);
}